// Round 1
// baseline (143.115 us; speedup 1.0000x reference)
//
#include <hip/hip_runtime.h>
#include <math.h>

// Problem constants (fixed by reference): B=32, T=2048, D=128
constexpr int B  = 32;
constexpr int T  = 2048;
constexpr int D  = 128;
constexpr int NW = T / 32;      // 64 packed 32-bit mask words per (b,d)
constexpr int C  = 16;          // legacy fallback kernel: timesteps per thread
constexpr int NC = T / C;       // 128 chunks per sequence

// =====================================================================
// Kernel 1: bit-pack the int32 mask into uint32 words over time.
// packed[b][w][d] bit i = (mask[b][w*32+i][d] != 0)
// Thread = (b, w, d4): 32 independent int4 loads -> 1 uint4 store.
// All traffic is 16B/lane (1KB per wave-instruction).
// =====================================================================
__global__ __launch_bounds__(256)
void pack_mask_kernel(const int* __restrict__ mask, unsigned* __restrict__ packed)
{
    const int gid = blockIdx.x * 256 + threadIdx.x;
    const int d4 = gid & 31;                 // d / 4
    const int w  = (gid >> 5) & (NW - 1);    // which 32-timestep word
    const int b  = gid >> 11;                // 32*64 = 2^11 threads per b

    const int4* m4 = reinterpret_cast<const int4*>(mask)
                   + (((size_t)(b * T + (w << 5)) * D) >> 2) + d4;
    unsigned r0 = 0, r1 = 0, r2 = 0, r3 = 0;
#pragma unroll
    for (int i = 0; i < 32; ++i) {
        const int4 m = m4[i * (D >> 2)];     // stride = one timestep (128 ints)
        r0 |= (m.x != 0 ? 1u : 0u) << i;
        r1 |= (m.y != 0 ? 1u : 0u) << i;
        r2 |= (m.z != 0 ? 1u : 0u) << i;
        r3 |= (m.w != 0 ? 1u : 0u) << i;
    }
    uint4 o; o.x = r0; o.y = r1; o.z = r2; o.w = r3;
    reinterpret_cast<uint4*>(packed + (size_t)(b * NW + w) * D)[d4] = o;
}

// =====================================================================
// Kernel 2: interpolation with float4 (d-vectorized) traffic.
// Thread = (b, chunk of 4 timesteps, 4 consecutive d).
// Carry lookup reads packed mask words (>=32-timestep window per side,
// fallback loop probability ~2^-32 per chain); all dependent carry
// fetches are issued as one independent batch.
// =====================================================================
__global__ __launch_bounds__(256)
void interp4_kernel(const float* __restrict__ values,
                    const float* __restrict__ times,
                    const unsigned* __restrict__ packed,
                    float* __restrict__ out)
{
    const int gid = blockIdx.x * 256 + threadIdx.x;
    const int d4 = gid & 31;                 // d / 4  (lanes: consecutive d4 -> coalesced)
    const int c  = (gid >> 5) & 511;         // chunk of 4 timesteps (T/4 = 512)
    const int b  = gid >> 14;                // 32*512 = 2^14 threads per b
    const int d0 = d4 << 2;
    const int t0 = c << 2;
    const int tw = t0 >> 5;                  // packed word holding this chunk
    const int sh = t0 & 31;                  // bit offset of chunk inside word (0..28)

    const size_t bbase = (size_t)b * T * D;
    const float* vrow = values + bbase + (size_t)t0 * D + d0;
    const float* trow = times  + bbase + (size_t)t0 * D + d0;

    // ---- phase 1: all independent wide loads ----
    float vv[4][4], tt[4][4];                // [timestep][chain]
#pragma unroll
    for (int i = 0; i < 4; ++i) {
        const float4 a = *reinterpret_cast<const float4*>(vrow + i * D);
        const float4 s = *reinterpret_cast<const float4*>(trow + i * D);
        vv[i][0] = a.x; vv[i][1] = a.y; vv[i][2] = a.z; vv[i][3] = a.w;
        tt[i][0] = s.x; tt[i][1] = s.y; tt[i][2] = s.z; tt[i][3] = s.w;
    }

    const unsigned* pk = packed + (size_t)b * NW * D;
    const uint4 pw    = *reinterpret_cast<const uint4*>(pk + (size_t)tw * D + d0);
    const uint4 pprev = (tw > 0)
        ? *reinterpret_cast<const uint4*>(pk + (size_t)(tw - 1) * D + d0) : make_uint4(0,0,0,0);
    const uint4 pnext = (tw < NW - 1)
        ? *reinterpret_cast<const uint4*>(pk + (size_t)(tw + 1) * D + d0) : make_uint4(0,0,0,0);

    const float4 tf4 = *reinterpret_cast<const float4*>(times + bbase + d0);
    const float4 tl4 = *reinterpret_cast<const float4*>(times + bbase + (size_t)(T - 1) * D + d0);
    const float tfirst[4] = {tf4.x, tf4.y, tf4.z, tf4.w};
    const float tlastT[4] = {tl4.x, tl4.y, tl4.z, tl4.w};

    const unsigned pwj[4] = {pw.x, pw.y, pw.z, pw.w};
    const unsigned ppj[4] = {pprev.x, pprev.y, pprev.z, pprev.w};
    const unsigned pnj[4] = {pnext.x, pnext.y, pnext.z, pnext.w};

    // ---- phase 2: carry indices per chain (register bit-scan only) ----
    int fi[4], bi[4];
#pragma unroll
    for (int j = 0; j < 4; ++j) {
        // forward: nearest observed index strictly before t0
        const unsigned wlow = sh ? (pwj[j] & ((1u << sh) - 1u)) : 0u;
        int f = -1;
        if (wlow)        f = (tw << 5) + 31 - __builtin_clz(wlow);
        else if (ppj[j]) f = ((tw - 1) << 5) + 31 - __builtin_clz(ppj[j]);
        else {
            for (int ww = tw - 2; ww >= 0; --ww) {      // ~never executes
                const unsigned x = pk[(size_t)ww * D + d0 + j];
                if (x) { f = (ww << 5) + 31 - __builtin_clz(x); break; }
            }
        }
        fi[j] = f;

        // backward: nearest observed index strictly after t0+3
        const int eh = sh + 4;                           // 4..32
        const unsigned whigh = (eh < 32) ? (pwj[j] >> eh) : 0u;
        int n = -1;
        if (whigh)       n = (tw << 5) + eh + __builtin_ctz(whigh);
        else if (pnj[j]) n = ((tw + 1) << 5) + __builtin_ctz(pnj[j]);
        else {
            for (int ww = tw + 2; ww < NW; ++ww) {      // ~never executes
                const unsigned x = pk[(size_t)ww * D + d0 + j];
                if (x) { n = (ww << 5) + __builtin_ctz(x); break; }
            }
        }
        bi[j] = n;
    }

    // ---- phase 3: issue ALL dependent carry fetches as one batch ----
    float fx[4], ft[4], bx[4], bt[4];
#pragma unroll
    for (int j = 0; j < 4; ++j) {
        const size_t offF = bbase + (size_t)(fi[j] < 0 ? 0 : fi[j]) * D + d0 + j;
        const size_t offB = bbase + (size_t)(bi[j] < 0 ? 0 : bi[j]) * D + d0 + j;
        fx[j] = values[offF]; ft[j] = times[offF];
        bx[j] = values[offB]; bt[j] = times[offB];
    }
#pragma unroll
    for (int j = 0; j < 4; ++j) {
        if (fi[j] < 0) { fx[j] = 0.f; ft[j] = tfirst[j]; }   // reference init
        if (bi[j] < 0) { bx[j] = 0.f; bt[j] = tlastT[j]; }   // reference init
    }

    // ---- phase 4: forward fill, reverse fill + interpolate ----
    float res[4][4];
#pragma unroll
    for (int j = 0; j < 4; ++j) {
        const unsigned mb = (pwj[j] >> sh) & 0xFu;
        float xl[4], tl[4];
        float cfx = fx[j], cft = ft[j];
#pragma unroll
        for (int i = 0; i < 4; ++i) {
            if ((mb >> i) & 1u) { cfx = vv[i][j]; cft = tt[i][j]; }
            xl[i] = cfx; tl[i] = cft;
        }
        float cbx = bx[j], cbt = bt[j];
#pragma unroll
        for (int i = 3; i >= 0; --i) {
            const bool obs = (mb >> i) & 1u;
            if (obs) { cbx = vv[i][j]; cbt = tt[i][j]; }
            const float denom = cbt - tl[i];
            const float num   = xl[i] * (cbt - tt[i][j]) + cbx * (tt[i][j] - tl[i]);
            const bool  safe  = (denom != 0.f);
            float xi = num / (safe ? denom : 1.f);
            xi = (safe && isfinite(xi)) ? xi : 0.f;
            res[i][j] = obs ? vv[i][j] : xi;
        }
    }

    float* orow = out + bbase + (size_t)t0 * D + d0;
#pragma unroll
    for (int i = 0; i < 4; ++i) {
        float4 o; o.x = res[i][0]; o.y = res[i][1]; o.z = res[i][2]; o.w = res[i][3];
        *reinterpret_cast<float4*>(orow + i * D) = o;
    }
}

// =====================================================================
// Legacy fallback (harness-verified, 46 us/dispatch): used only if the
// workspace is too small for the packed mask.
// =====================================================================
__global__ __launch_bounds__(256)
void linterp_kernel(const float* __restrict__ values,
                    const float* __restrict__ times,
                    const int*   __restrict__ mask,
                    float*       __restrict__ out)
{
    const int gid   = blockIdx.x * 256 + threadIdx.x;
    const int d     = gid & (D - 1);
    const int chunk = (gid >> 7) & (NC - 1);
    const int b     = gid >> 14;

    const int seq_base = b * T * D + d;
    const int t0i      = chunk * C;

    float v[C], tm[C];
    unsigned int mbits = 0;
#pragma unroll
    for (int i = 0; i < C; ++i) {
        const int off = seq_base + (t0i + i) * D;
        v[i]  = values[off];
        tm[i] = times[off];
        mbits |= (mask[off] != 0 ? 1u : 0u) << i;
    }

    const float t_first = times[seq_base];
    const float t_lastT = times[seq_base + (T - 1) * D];

    float fx = 0.f, ft = t_first;
    if (chunk > 0) {
        unsigned int pb = 0;
#pragma unroll
        for (int i = 0; i < C; ++i) {
            const int off = seq_base + (t0i - C + i) * D;
            pb |= (mask[off] != 0 ? 1u : 0u) << i;
        }
        if (pb != 0u) {
            const int idx = 31 - __builtin_clz(pb);
            const int off = seq_base + (t0i - C + idx) * D;
            fx = values[off]; ft = times[off];
        } else {
            for (int j = t0i - C - 1; j >= 0; --j) {
                const int off = seq_base + j * D;
                if (mask[off] != 0) { fx = values[off]; ft = times[off]; break; }
            }
        }
    }

    float bxv = 0.f, btv = t_lastT;
    if (chunk < NC - 1) {
        unsigned int nb = 0;
#pragma unroll
        for (int i = 0; i < C; ++i) {
            const int off = seq_base + (t0i + C + i) * D;
            nb |= (mask[off] != 0 ? 1u : 0u) << i;
        }
        if (nb != 0u) {
            const int idx = __builtin_ctz(nb);
            const int off = seq_base + (t0i + C + idx) * D;
            bxv = values[off]; btv = times[off];
        } else {
            for (int j = t0i + 2 * C; j < T; ++j) {
                const int off = seq_base + j * D;
                if (mask[off] != 0) { bxv = values[off]; btv = times[off]; break; }
            }
        }
    }

    float xl[C], tl[C];
#pragma unroll
    for (int i = 0; i < C; ++i) {
        if ((mbits >> i) & 1u) { fx = v[i]; ft = tm[i]; }
        xl[i] = fx;
        tl[i] = ft;
    }

#pragma unroll
    for (int i = C - 1; i >= 0; --i) {
        const bool obs = (mbits >> i) & 1u;
        if (obs) { bxv = v[i]; btv = tm[i]; }
        const float denom = btv - tl[i];
        const float num   = xl[i] * (btv - tm[i]) + bxv * (tm[i] - tl[i]);
        const bool  safe  = (denom != 0.f);
        float xi = num / (safe ? denom : 1.f);
        xi = (safe && isfinite(xi)) ? xi : 0.f;
        out[seq_base + (t0i + i) * D] = obs ? v[i] : xi;
    }
}

extern "C" void kernel_launch(void* const* d_in, const int* in_sizes, int n_in,
                              void* d_out, int out_size, void* d_ws, size_t ws_size,
                              hipStream_t stream)
{
    const float* values = (const float*)d_in[0];
    const float* times  = (const float*)d_in[1];
    const int*   mask   = (const int*)d_in[2];
    float*       out    = (float*)d_out;

    const size_t PACKED_BYTES = (size_t)B * NW * D * sizeof(unsigned);  // 1 MiB
    if (d_ws != nullptr && ws_size >= PACKED_BYTES) {
        unsigned* packed = (unsigned*)d_ws;
        pack_mask_kernel<<<(B * NW * (D / 4)) / 256, 256, 0, stream>>>(mask, packed);
        interp4_kernel<<<(B * (T / 4) * (D / 4)) / 256, 256, 0, stream>>>(values, times, packed, out);
    } else {
        linterp_kernel<<<(B * NC * D) / 256, 256, 0, stream>>>(values, times, mask, out);
    }
}